// Round 2
// baseline (272.888 us; speedup 1.0000x reference)
//
#include <hip/hip_runtime.h>
#include <cstdint>
#include <cstddef>

#define NB 8
#define NS 2048
#define ND 768
#define NSP 512
#define MAXW 30
#define NH 100
#define LDP 104   // P row stride: cols 0..99 = h, col 100 = attention logit

// Kernel 1: P[row, h] = seq[row,:]·ffnn_w[:,h]  (h<100);  P[row,100] = seq[row,:]·att_w
// fp32 register-tile GEMM: 64 rows/block, N=128 logical (101 real), BK=32.
// 256 threads = 16 row-groups (4 rows) x 16 col-groups (cols {2c,2c+1}+{0,32,64,96}).
__global__ __launch_bounds__(256) void proj_kernel(
    const float* __restrict__ seq, const float* __restrict__ ffnn_w,
    const float* __restrict__ att_w, float* __restrict__ P)
{
    __shared__ float As[32][68];    // [k][m]; stride 68 floats = 272 B (16B-aligned)
    __shared__ float Ws[32][132];   // [k][col]; cols 0..100 valid, 101..127 read-garbage (never stored)

    const int t = threadIdx.x;
    const int m0 = blockIdx.x * 64;
    const int mt = t & 15;          // rows 4*mt .. 4*mt+3
    const int ct = t >> 4;          // cols 2*ct + {0,1} in each 32-col group

    float acc[4][8];
#pragma unroll
    for (int r = 0; r < 4; r++)
#pragma unroll
        for (int c = 0; c < 8; c++) acc[r][c] = 0.f;

    for (int kt = 0; kt < ND / 32; ++kt) {
        const int k0 = kt * 32;
        // stage A tile (64 rows x 32 k), transposed to [k][m]
#pragma unroll
        for (int j = 0; j < 2; ++j) {
            int f = t + j * 256;            // 512 float4 = 64 rows x 8
            int row = f >> 3, k4 = f & 7;
            float4 v = *(const float4*)&seq[(size_t)(m0 + row) * ND + k0 + k4 * 4];
            As[k4 * 4 + 0][row] = v.x;
            As[k4 * 4 + 1][row] = v.y;
            As[k4 * 4 + 2][row] = v.z;
            As[k4 * 4 + 3][row] = v.w;
        }
        // stage W chunk (32 k x 100 cols) + att_w as col 100
        for (int idx = t; idx < 32 * NH; idx += 256) {
            int r = idx / NH, c = idx - r * NH;
            Ws[r][c] = ffnn_w[(size_t)(k0 + r) * NH + c];
        }
        if (t < 32) Ws[t][NH] = att_w[k0 + t];
        __syncthreads();

#pragma unroll 8
        for (int kk = 0; kk < 32; ++kk) {
            float4 a = *(const float4*)&As[kk][4 * mt];
            float av[4] = {a.x, a.y, a.z, a.w};
#pragma unroll
            for (int g = 0; g < 4; ++g) {
                float2 w = *(const float2*)&Ws[kk][g * 32 + 2 * ct];
#pragma unroll
                for (int r = 0; r < 4; ++r) {
                    acc[r][2 * g]     += av[r] * w.x;
                    acc[r][2 * g + 1] += av[r] * w.y;
                }
            }
        }
        __syncthreads();
    }

#pragma unroll
    for (int r = 0; r < 4; ++r) {
        size_t row = (size_t)(m0 + 4 * mt + r);
#pragma unroll
        for (int g = 0; g < 4; ++g)
#pragma unroll
            for (int j = 0; j < 2; ++j) {
                int col = g * 32 + 2 * ct + j;
                if (col <= NH) P[row * LDP + col] = acc[r][2 * g + j];
            }
    }
}

// Kernel 2: one wave per span. Softmax over logits (P col 100; att_b cancels),
// then out[n,h] = tanh(mask * sum_i attn_i * P[start+i, h] + b_h).
__global__ __launch_bounds__(256) void span_kernel(
    const int* __restrict__ span_idx, const int* __restrict__ span_mask,
    const float* __restrict__ P, const float* __restrict__ ffnn_b,
    float* __restrict__ out)
{
    const int wave = threadIdx.x >> 6, lane = threadIdx.x & 63;
    const int gs = blockIdx.x * 4 + wave;          // [0, 4096)
    const int b = gs / NSP;
    const int st = span_idx[2 * gs];
    int w = span_idx[2 * gs + 1] - st;             // width in [1, MAXW]
    w = max(1, min(w, MAXW));

    const float* Pb = P + ((size_t)b * NS + st) * LDP;

    // masked softmax over span width (lanes 0..w-1 hold elements)
    float lg = (lane < w) ? Pb[lane * LDP + NH] : -1e30f;
    float mx = lg;
#pragma unroll
    for (int off = 32; off > 0; off >>= 1) mx = fmaxf(mx, __shfl_xor(mx, off));
    float e = (lane < w) ? expf(lg - mx) : 0.f;
    float sum = e;
#pragma unroll
    for (int off = 32; off > 0; off >>= 1) sum += __shfl_xor(sum, off);
    float attn = e / sum;

    // attended projection: lanes = h dim (coalesced P-row reads)
    float acc0 = 0.f, acc1 = 0.f;
    for (int i = 0; i < w; ++i) {
        float a = __shfl(attn, i);
        const float* Pr = Pb + i * LDP;
        acc0 += a * Pr[lane];
        if (lane < NH - 64) acc1 += a * Pr[64 + lane];
    }

    float m = (float)span_mask[gs];
    out[(size_t)gs * NH + lane] = tanhf(m * acc0 + ffnn_b[lane]);
    if (lane < NH - 64)
        out[(size_t)gs * NH + 64 + lane] = tanhf(m * acc1 + ffnn_b[64 + lane]);
}

extern "C" void kernel_launch(void* const* d_in, const int* in_sizes, int n_in,
                              void* d_out, int out_size, void* d_ws, size_t ws_size,
                              hipStream_t stream) {
    const float* seq      = (const float*)d_in[0];  // [B,S,D]
    const int*   span_idx = (const int*)d_in[1];    // [B,N,2] int32 on device
    const int*   span_msk = (const int*)d_in[2];    // [B,N]
    const float* att_w    = (const float*)d_in[3];  // [D,1]
    // d_in[4] = att_b: cancels inside softmax (shift invariance) — unused
    const float* ffnn_w   = (const float*)d_in[5];  // [D,H]
    const float* ffnn_b   = (const float*)d_in[6];  // [H]
    float* out = (float*)d_out;                     // [B,N,H]

    float* P = (float*)d_ws;                        // [B*S, LDP] = 6.8 MB

    proj_kernel<<<(NB * NS) / 64, 256, 0, stream>>>(seq, ffnn_w, att_w, P);
    span_kernel<<<(NB * NSP) / 4, 256, 0, stream>>>(span_idx, span_msk, P, ffnn_b, out);
}

// Round 4
// 126.691 us; speedup vs baseline: 2.1540x; 2.1540x over previous
//
#include <hip/hip_runtime.h>
#include <cstdint>
#include <cstddef>

#define NB 8
#define NS 2048
#define ND 768
#define NSP 512
#define MAXW 30
#define NH 100
#define LDP 104        // P row stride: cols 0..99 = h, col 100 = attention logit
#define NKS (ND / 32)  // 24 k-steps of 32

typedef __attribute__((ext_vector_type(8))) short short8;
typedef __attribute__((ext_vector_type(4))) float floatx4;

// float -> bf16 (round to nearest even), manual bit twiddle (no __hip_bfloat16 ABI)
__device__ inline unsigned short f2bf(float f) {
    unsigned u = __float_as_uint(f);
    return (unsigned short)((u + 0x7fffu + ((u >> 16) & 1u)) >> 16);
}
__device__ inline float bf2f(unsigned short h) {
    return __uint_as_float(((unsigned)h) << 16);
}

union PackUS { unsigned short us[8]; uint4 v; short8 s8; };

// Kernel 0: pack B = [ffnn_w | att_w | 0-pad] (768 x 128) into MFMA B-fragment order, bf16.
// Frag (ks, cf): lane l holds B[k = ks*32 + (l>>4)*8 + j][n = cf*16 + (l&15)], j=0..7.
__global__ __launch_bounds__(256) void pack_b_kernel(
    const float* __restrict__ ffnn_w, const float* __restrict__ att_w,
    uint4* __restrict__ Bfrag)
{
    int ks = blockIdx.x;
    for (int idx = threadIdx.x; idx < 8 * 64; idx += 256) {
        int cf = idx >> 6, lane = idx & 63;
        int q = lane >> 4, r = lane & 15;
        int n = cf * 16 + r;
        PackUS p;
#pragma unroll
        for (int j = 0; j < 8; j++) {
            int k = ks * 32 + q * 8 + j;
            float v = (n < NH) ? ffnn_w[(size_t)k * NH + n]
                               : (n == NH ? att_w[k] : 0.f);
            p.us[j] = f2bf(v);
        }
        Bfrag[(size_t)(ks * 8 + cf) * 64 + lane] = p.v;
    }
}

__device__ inline void split8(const float* x, short8& hi, short8& lo) {
    PackUS ph, pl;
#pragma unroll
    for (int i = 0; i < 8; i++) {
        unsigned short h = f2bf(x[i]);
        ph.us[i] = h;
        pl.us[i] = f2bf(x[i] - bf2f(h));
    }
    hi = ph.s8;
    lo = pl.s8;
}

// Kernel 1: P[row, 0..100] = seq[row,:]·[ffnn_w | att_w]  via split-A bf16 MFMA.
// 512 blocks x 4 waves; wave = 16 rows x 64 cols; no LDS, no barriers.
__global__ __launch_bounds__(256) void proj_kernel(
    const float* __restrict__ seq, const uint4* __restrict__ Bfrag,
    float* __restrict__ P)
{
    const int t = threadIdx.x;
    const int wave = t >> 6, lane = t & 63;
    const int q = lane >> 4, r = lane & 15;
    const int rf = wave >> 1;              // row-frag 0/1
    const int cfbase = (wave & 1) * 4;     // col-frags cfbase..cfbase+3
    const int row0 = blockIdx.x * 32 + rf * 16;

    floatx4 acc[4] = {{0.f, 0.f, 0.f, 0.f}, {0.f, 0.f, 0.f, 0.f},
                      {0.f, 0.f, 0.f, 0.f}, {0.f, 0.f, 0.f, 0.f}};

    const float* arow = seq + (size_t)(row0 + r) * ND + q * 8;

#pragma unroll 2
    for (int ks = 0; ks < NKS; ++ks) {
        float av[8];
        *(float4*)&av[0] = *(const float4*)(arow + ks * 32);
        *(float4*)&av[4] = *(const float4*)(arow + ks * 32 + 4);
        short8 ahi, alo;
        split8(av, ahi, alo);
#pragma unroll
        for (int c = 0; c < 4; ++c) {
            PackUS pb;
            pb.v = Bfrag[(size_t)(ks * 8 + cfbase + c) * 64 + lane];
            acc[c] = __builtin_amdgcn_mfma_f32_16x16x32_bf16(ahi, pb.s8, acc[c], 0, 0, 0);
            acc[c] = __builtin_amdgcn_mfma_f32_16x16x32_bf16(alo, pb.s8, acc[c], 0, 0, 0);
        }
    }

    // C/D layout: col = lane&15, row = q*4 + reg
#pragma unroll
    for (int c = 0; c < 4; ++c) {
        int col = (cfbase + c) * 16 + r;
        if (col <= NH) {
#pragma unroll
            for (int reg = 0; reg < 4; ++reg)
                P[(size_t)(row0 + q * 4 + reg) * LDP + col] = acc[c][reg];
        }
    }
}

// Kernel 2: one wave per span. Softmax over P col 100 (att_b cancels), then
// out[n,h] = tanh(mask * sum_i attn_i * P[start+i, h] + b_h).
__global__ __launch_bounds__(256) void span_kernel(
    const int* __restrict__ span_idx, const int* __restrict__ span_mask,
    const float* __restrict__ P, const float* __restrict__ ffnn_b,
    float* __restrict__ out)
{
    const int wave = threadIdx.x >> 6, lane = threadIdx.x & 63;
    const int gs = blockIdx.x * 4 + wave;          // [0, 4096)
    const int b = gs / NSP;
    const int st = span_idx[2 * gs];
    int w = span_idx[2 * gs + 1] - st;             // width in [1, MAXW]
    w = max(1, min(w, MAXW));

    const float* Pb = P + ((size_t)b * NS + st) * LDP;

    // masked softmax over span width (lanes 0..w-1 hold elements)
    float lg = (lane < w) ? Pb[lane * LDP + NH] : -1e30f;
    float mx = lg;
#pragma unroll
    for (int off = 32; off > 0; off >>= 1) mx = fmaxf(mx, __shfl_xor(mx, off));
    float e = (lane < w) ? expf(lg - mx) : 0.f;
    float sum = e;
#pragma unroll
    for (int off = 32; off > 0; off >>= 1) sum += __shfl_xor(sum, off);
    float attn = e / sum;                          // 0 for lanes >= w

    // attended: lanes = h dim. Fixed trip count (starts < S-MAXW => in bounds;
    // attn_i == 0 for i >= w) so all loads issue unrolled.
    float acc0 = 0.f, acc1 = 0.f;
#pragma unroll
    for (int i = 0; i < MAXW; ++i) {
        float a = __shfl(attn, i);
        const float* Pr = Pb + i * LDP;
        acc0 += a * Pr[lane];
        if (lane < NH - 64) acc1 += a * Pr[64 + lane];
    }

    float m = (float)span_mask[gs];
    out[(size_t)gs * NH + lane] = tanhf(m * acc0 + ffnn_b[lane]);
    if (lane < NH - 64)
        out[(size_t)gs * NH + 64 + lane] = tanhf(m * acc1 + ffnn_b[64 + lane]);
}

extern "C" void kernel_launch(void* const* d_in, const int* in_sizes, int n_in,
                              void* d_out, int out_size, void* d_ws, size_t ws_size,
                              hipStream_t stream) {
    const float* seq      = (const float*)d_in[0];  // [B,S,D]
    const int*   span_idx = (const int*)d_in[1];    // [B,N,2] int32 on device
    const int*   span_msk = (const int*)d_in[2];    // [B,N]
    const float* att_w    = (const float*)d_in[3];  // [D,1]
    // d_in[4] = att_b: cancels inside softmax — unused
    const float* ffnn_w   = (const float*)d_in[5];  // [D,H]
    const float* ffnn_b   = (const float*)d_in[6];  // [H]
    float* out = (float*)d_out;                     // [B,N,H]

    float* P = (float*)d_ws;                                   // 16384*104*4 = 6.8 MB
    uint4* Bfrag = (uint4*)((char*)d_ws + (size_t)NB * NS * LDP * 4);  // 192 KB

    pack_b_kernel<<<NKS, 256, 0, stream>>>(ffnn_w, att_w, Bfrag);
    proj_kernel<<<(NB * NS) / 32, 256, 0, stream>>>(seq, Bfrag, P);
    span_kernel<<<(NB * NSP) / 4, 256, 0, stream>>>(span_idx, span_msk, P, ffnn_b, out);
}